// Round 3
// baseline (1461.883 us; speedup 1.0000x reference)
//
#include <hip/hip_runtime.h>

#define S 207
#define BATCH 128
#define NPTS 256000

static const int OFFS[19] = {0,8,16,24,32,40,56,72,88,104,128,152,176,200,232,264,296,328,392};

__global__ void zero2_kernel(float4* __restrict__ a, float4* __restrict__ b, int n4) {
    int i = blockIdx.x * blockDim.x + threadIdx.x;
    if (i < n4) { a[i] = make_float4(0,0,0,0); b[i] = make_float4(0,0,0,0); }
}

__global__ void zero_kernel(float* __restrict__ p, int n) {
    int i = blockIdx.x * blockDim.x + threadIdx.x;
    if (i < n) p[i] = 0.0f;
}

__global__ void scatter_kernel(const int* __restrict__ loc, const int* __restrict__ bidx,
                               const float* __restrict__ feat,
                               float* __restrict__ xs, float* __restrict__ ms) {
    int t = blockIdx.x * blockDim.x + threadIdx.x;
    if (t >= NPTS) return;
    int b = bidx[t];
    int r = loc[2 * t];
    int c = loc[2 * t + 1];
    int idx = (b * S + r) * S + c;
    atomicAdd(&xs[idx], feat[t]);
    ms[idx] = 1.0f;
}

// Fused conv0(SAME)*m -> masked 3x2 maxpool. One thread per output pixel, all 8 channels.
__global__ __launch_bounds__(256) void conv0_pool_kernel(
    const float* __restrict__ xs, const float* __restrict__ ms,
    const float* __restrict__ w,   // (3,3,1,8)
    float* __restrict__ x1, float* __restrict__ m1) {
    const int Hout = 103;
    int opix = blockIdx.x * 256 + threadIdx.x;
    int total = BATCH * Hout * Hout;
    if (opix >= total) return;
    int wo = opix % Hout;
    int t = opix / Hout;
    int ho = t % Hout;
    int b  = t / Hout;

    float mv[3][3];
    float mwin = 0.0f;
    #pragma unroll
    for (int pi = 0; pi < 3; ++pi)
        #pragma unroll
        for (int pj = 0; pj < 3; ++pj) {
            float m = ms[(b * S + 2 * ho + pi) * S + 2 * wo + pj];
            mv[pi][pj] = m;
            mwin = fmaxf(mwin, m);
        }
    float* xp = x1 + (size_t)opix * 8;
    if (mwin <= 0.0f) {
        *(float4*)xp = make_float4(0,0,0,0);
        *(float4*)(xp + 4) = make_float4(0,0,0,0);
        m1[opix] = 0.0f;
        return;
    }
    float p[5][5];
    #pragma unroll
    for (int r = 0; r < 5; ++r) {
        int ii = 2 * ho - 1 + r;
        #pragma unroll
        for (int c = 0; c < 5; ++c) {
            int jj = 2 * wo - 1 + c;
            bool ok = ((unsigned)ii < (unsigned)S) && ((unsigned)jj < (unsigned)S);
            p[r][c] = ok ? xs[(b * S + ii) * S + jj] : 0.0f;
        }
    }
    float best[8];
    #pragma unroll
    for (int co = 0; co < 8; ++co) best[co] = -1e30f;
    #pragma unroll
    for (int pi = 0; pi < 3; ++pi)
        #pragma unroll
        for (int pj = 0; pj < 3; ++pj) {
            if (mv[pi][pj] > 0.0f) {
                float acc[8];
                #pragma unroll
                for (int co = 0; co < 8; ++co) acc[co] = 0.0f;
                #pragma unroll
                for (int kh = 0; kh < 3; ++kh)
                    #pragma unroll
                    for (int kw = 0; kw < 3; ++kw) {
                        float x = p[pi + kh][pj + kw];
                        #pragma unroll
                        for (int co = 0; co < 8; ++co)
                            acc[co] = fmaf(x, w[(kh * 3 + kw) * 8 + co], acc[co]);
                    }
                #pragma unroll
                for (int co = 0; co < 8; ++co) best[co] = fmaxf(best[co], acc[co]);
            }
        }
    *(float4*)xp = make_float4(best[0], best[1], best[2], best[3]);
    *(float4*)(xp + 4) = make_float4(best[4], best[5], best[6], best[7]);
    m1[opix] = 1.0f;
}

// Fused full residual block (stride 1, CIN==COUT==C):
// out = conv(bnrelu(conv(bnrelu(x,g1,b1))*m, g2, b2))*m + x
// One 16x16 output tile per block; intermediate kept in LDS with 1-pixel halo.
template <int C, int TILE, int NTX>
__global__ __launch_bounds__(256) void fused_pair_kernel(
    const float* __restrict__ in, const float* __restrict__ mask,
    const float* __restrict__ w1g, const float* __restrict__ w2g,
    const float* __restrict__ g1, const float* __restrict__ bb1,
    const float* __restrict__ g2, const float* __restrict__ bb2,
    float* __restrict__ out, int H) {
    constexpr int XT = TILE + 4;   // input patch (2-halo)
    constexpr int HT = TILE + 2;   // intermediate (1-halo)
    constexpr int CP = C + 1;      // padded pixel stride -> LDS conflict-free
    __shared__ float xs[XT * XT * CP];
    __shared__ float msh[XT * XT];
    __shared__ float h1[HT * HT * CP];
    __shared__ float resb[TILE * TILE * CP];
    __shared__ float w1s[9 * C * C], w2s[9 * C * C];

    int tid = threadIdx.x;
    int bid = blockIdx.x;
    int b = bid / (NTX * NTX);
    int t = bid % (NTX * NTX);
    int r0 = (t / NTX) * TILE, c0 = (t % NTX) * TILE;

    // phase 1: load raw x patch + mask + weights
    for (int i = tid; i < XT * XT * C; i += 256) {
        int pix = i / C, c = i % C;
        int py = pix / XT, px = pix % XT;
        int gy = r0 - 2 + py, gx = c0 - 2 + px;
        float v = 0.0f;
        if ((unsigned)gy < (unsigned)H && (unsigned)gx < (unsigned)H)
            v = in[((size_t)(b * H + gy) * H + gx) * C + c];
        xs[pix * CP + c] = v;
    }
    for (int i = tid; i < XT * XT; i += 256) {
        int py = i / XT, px = i % XT;
        int gy = r0 - 2 + py, gx = c0 - 2 + px;
        float v = 0.0f;
        if ((unsigned)gy < (unsigned)H && (unsigned)gx < (unsigned)H)
            v = mask[(size_t)(b * H + gy) * H + gx];
        msh[i] = v;
    }
    for (int i = tid; i < 9 * C * C; i += 256) { w1s[i] = w1g[i]; w2s[i] = w2g[i]; }
    __syncthreads();

    // phase 2: stash raw center for the residual
    for (int i = tid; i < TILE * TILE * C; i += 256) {
        int pix = i / C, c = i % C;
        int ty = pix / TILE, tx = pix % TILE;
        resb[pix * CP + c] = xs[((ty + 2) * XT + tx + 2) * CP + c];
    }
    __syncthreads();

    // phase 3: bnrelu(x, m, g1, b1) in place
    for (int i = tid; i < XT * XT * C; i += 256) {
        int pix = i / C, c = i % C;
        xs[pix * CP + c] = msh[pix] * fmaxf(fmaf(xs[pix * CP + c], g1[c], bb1[c]), 0.0f);
    }
    __syncthreads();

    // phase 4: h1 = conv3x3(xs) * m  over the 1-halo region
    for (int pos = tid; pos < HT * HT; pos += 256) {
        int py = pos / HT, px = pos % HT;
        float mc = msh[(py + 1) * XT + px + 1];
        if (mc > 0.0f) {
            float acc[C];
            #pragma unroll
            for (int co = 0; co < C; ++co) acc[co] = 0.0f;
            #pragma unroll
            for (int kh = 0; kh < 3; ++kh)
                #pragma unroll
                for (int kw = 0; kw < 3; ++kw) {
                    const float* xp = &xs[((py + kh) * XT + px + kw) * CP];
                    #pragma unroll
                    for (int ci = 0; ci < C; ++ci) {
                        float xv = xp[ci];
                        const float* wp = &w1s[((kh * 3 + kw) * C + ci) * C];
                        #pragma unroll
                        for (int co = 0; co < C; ++co)
                            acc[co] = fmaf(xv, wp[co], acc[co]);
                    }
                }
            #pragma unroll
            for (int co = 0; co < C; ++co) h1[pos * CP + co] = acc[co] * mc;
        } else {
            #pragma unroll
            for (int co = 0; co < C; ++co) h1[pos * CP + co] = 0.0f;
        }
    }
    __syncthreads();

    // phase 5: bnrelu(h1, m, g2, b2) in place
    for (int i = tid; i < HT * HT * C; i += 256) {
        int pos = i / C, c = i % C;
        float m = msh[(pos / HT + 1) * XT + (pos % HT) + 1];
        h1[pos * CP + c] = m * fmaxf(fmaf(h1[pos * CP + c], g2[c], bb2[c]), 0.0f);
    }
    __syncthreads();

    // phase 6: out = conv3x3(h1)*m + res
    {
        int ty = tid / TILE, tx = tid % TILE;
        int gy = r0 + ty, gx = c0 + tx;
        if (gy < H && gx < H) {
            float mo = msh[(ty + 2) * XT + tx + 2];
            float acc[C];
            #pragma unroll
            for (int co = 0; co < C; ++co) acc[co] = 0.0f;
            if (mo > 0.0f) {
                #pragma unroll
                for (int kh = 0; kh < 3; ++kh)
                    #pragma unroll
                    for (int kw = 0; kw < 3; ++kw) {
                        const float* hp = &h1[((ty + kh) * HT + tx + kw) * CP];
                        #pragma unroll
                        for (int ci = 0; ci < C; ++ci) {
                            float xv = hp[ci];
                            const float* wp = &w2s[((kh * 3 + kw) * C + ci) * C];
                            #pragma unroll
                            for (int co = 0; co < C; ++co)
                                acc[co] = fmaf(xv, wp[co], acc[co]);
                        }
                    }
            }
            float* op = out + ((size_t)(b * H + gy) * H + gx) * C;
            #pragma unroll
            for (int j = 0; j < C; j += 4) {
                float4 o4;
                o4.x = acc[j]     * mo + resb[tid * CP + j];
                o4.y = acc[j + 1] * mo + resb[tid * CP + j + 1];
                o4.z = acc[j + 2] * mo + resb[tid * CP + j + 2];
                o4.w = acc[j + 3] * mo + resb[tid * CP + j + 3];
                *(float4*)(op + j) = o4;
            }
        }
    }
}

// Fused conv: optionally bnrelu on input, conv, * mOut, [+ res].
template <int K, int CIN, int COUT, int COT, bool BN, bool RES>
__global__ __launch_bounds__(256) void fconv_kernel(
    const float* __restrict__ in, const float* __restrict__ w,
    const float* __restrict__ g, const float* __restrict__ bbn,
    const float* __restrict__ mIn, const float* __restrict__ mOut,
    const float* __restrict__ res, float* __restrict__ out,
    int Hin, int Hout, int stride, int pad) {
    const int Win = Hin, Wout = Hout;
    int npix = BATCH * Hout * Wout;
    int opix = blockIdx.x * 256 + threadIdx.x;
    if (opix >= npix) return;
    int co0 = blockIdx.y * COT;
    int wo = opix % Wout;
    int t = opix / Wout;
    int ho = t % Hout;
    int b  = t / Hout;

    float mo = mOut[opix];
    float* op = out + (size_t)opix * COUT + co0;
    if (mo <= 0.0f) {
        #pragma unroll
        for (int j = 0; j < COT; j += 4) {
            float4 r4 = RES ? *(const float4*)(res + (size_t)opix * COUT + co0 + j)
                            : make_float4(0,0,0,0);
            *(float4*)(op + j) = r4;
        }
        return;
    }
    float acc[COT];
    #pragma unroll
    for (int j = 0; j < COT; ++j) acc[j] = 0.0f;

    #pragma unroll
    for (int kh = 0; kh < K; ++kh) {
        int ih = ho * stride + kh - pad;
        if ((unsigned)ih >= (unsigned)Hin) continue;
        #pragma unroll
        for (int kw = 0; kw < K; ++kw) {
            int iw = wo * stride + kw - pad;
            if ((unsigned)iw >= (unsigned)Win) continue;
            int ipix = (b * Hin + ih) * Win + iw;
            float mi = 1.0f;
            if (BN) { mi = mIn[ipix]; if (mi <= 0.0f) continue; }
            const float* ip = in + (size_t)ipix * CIN;
            const float* wp = w + (kh * K + kw) * CIN * COUT + co0;
            #pragma unroll
            for (int ci = 0; ci < CIN; ci += 4) {
                float4 xv = *(const float4*)(ip + ci);
                if (BN) {
                    xv.x = mi * fmaxf(fmaf(xv.x, g[ci],     bbn[ci]),     0.0f);
                    xv.y = mi * fmaxf(fmaf(xv.y, g[ci + 1], bbn[ci + 1]), 0.0f);
                    xv.z = mi * fmaxf(fmaf(xv.z, g[ci + 2], bbn[ci + 2]), 0.0f);
                    xv.w = mi * fmaxf(fmaf(xv.w, g[ci + 3], bbn[ci + 3]), 0.0f);
                }
                #pragma unroll
                for (int j = 0; j < COT; ++j) {
                    acc[j] = fmaf(xv.x, wp[(ci    ) * COUT + j], acc[j]);
                    acc[j] = fmaf(xv.y, wp[(ci + 1) * COUT + j], acc[j]);
                    acc[j] = fmaf(xv.z, wp[(ci + 2) * COUT + j], acc[j]);
                    acc[j] = fmaf(xv.w, wp[(ci + 3) * COUT + j], acc[j]);
                }
            }
        }
    }
    #pragma unroll
    for (int j = 0; j < COT; j += 4) {
        float4 o4;
        o4.x = acc[j] * mo; o4.y = acc[j+1] * mo; o4.z = acc[j+2] * mo; o4.w = acc[j+3] * mo;
        if (RES) {
            float4 r4 = *(const float4*)(res + (size_t)opix * COUT + co0 + j);
            o4.x += r4.x; o4.y += r4.y; o4.z += r4.z; o4.w += r4.w;
        }
        *(float4*)(op + j) = o4;
    }
}

__global__ void pool_kernel(const float* __restrict__ in, float* __restrict__ out,
                            int Hin, int Win, int Hout, int Wout, int win, int stride) {
    int tid = blockIdx.x * blockDim.x + threadIdx.x;
    int total = BATCH * Hout * Wout;
    if (tid >= total) return;
    int wo = tid % Wout;
    int p = tid / Wout;
    int ho = p % Hout;
    int b  = p / Hout;
    float mx = 0.0f;
    for (int i = 0; i < win; ++i)
        for (int j = 0; j < win; ++j)
            mx = fmaxf(mx, in[(b * Hin + ho * stride + i) * Win + wo * stride + j]);
    out[tid] = mx;
}

// bnrelu(g17,b17) + flatten to NCHW-flat layout: xt[b][c*64+hw]
__global__ __launch_bounds__(256) void bn_tr_kernel(
    const float* __restrict__ x, const float* __restrict__ m,
    const float* __restrict__ g, const float* __restrict__ bb,
    float* __restrict__ xt) {
    int tid = blockIdx.x * 256 + threadIdx.x;
    if (tid >= BATCH * 4096) return;
    int c = tid & 63, hw = (tid >> 6) & 63, b = tid >> 12;
    float v = m[b * 64 + hw] * fmaxf(fmaf(x[tid], g[c], bb[c]), 0.0f);
    xt[((size_t)b << 12) + c * 64 + hw] = v;
}

// C[128,100] += xt[128,4096] . wl[100,4096]^T, split-K with atomics.
// grid (100, 8); per block: o uniform, waves span b, 2 k-subchunks of 256.
__global__ __launch_bounds__(256) void linear_gemm_kernel(
    const float* __restrict__ xt, const float* __restrict__ wl,
    float* __restrict__ out) {
    int o = blockIdx.x;
    int half = threadIdx.x >> 7;
    int b = threadIdx.x & 127;
    int k0 = blockIdx.y * 512 + half * 256;
    const float* xp = xt + ((size_t)b << 12) + k0;
    const float* wp = wl + o * 4096 + k0;
    float acc = 0.0f;
    #pragma unroll 16
    for (int k = 0; k < 256; k += 4) {
        float4 xv = *(const float4*)(xp + k);
        float4 wv = *(const float4*)(wp + k);
        acc = fmaf(xv.x, wv.x, acc); acc = fmaf(xv.y, wv.y, acc);
        acc = fmaf(xv.z, wv.z, acc); acc = fmaf(xv.w, wv.w, acc);
    }
    atomicAdd(&out[b * 100 + o], acc);
}

template <int K, int CIN, int COUT, int COT, bool BN, bool RES>
static inline void fconv(hipStream_t s, const float* in, const float* w,
                         const float* g, const float* bbn,
                         const float* mIn, const float* mOut, const float* res,
                         float* out, int Hin, int Hout, int stride, int pad) {
    int npix = BATCH * Hout * Hout;
    dim3 grid((npix + 255) / 256, COUT / COT);
    fconv_kernel<K, CIN, COUT, COT, BN, RES><<<grid, 256, 0, s>>>(
        in, w, g, bbn, mIn, mOut, res, out, Hin, Hout, stride, pad);
}

extern "C" void kernel_launch(void* const* d_in, const int* in_sizes, int n_in,
                              void* d_out, int out_size, void* d_ws, size_t ws_size,
                              hipStream_t stream) {
    const int*   loc   = (const int*)d_in[0];
    const int*   bidx  = (const int*)d_in[1];
    const float* feat  = (const float*)d_in[2];
    const float* gamma = (const float*)d_in[3];
    const float* beta  = (const float*)d_in[4];
    const float* Wconv0 = (const float*)d_in[5];
    const float* Wc1a = (const float*)d_in[6];
    const float* Wc1b = (const float*)d_in[7];
    const float* Wc2a = (const float*)d_in[8];
    const float* Wc2b = (const float*)d_in[9];
    const float* Wc3a = (const float*)d_in[10];
    const float* Wc3b = (const float*)d_in[11];
    const float* Wc3r = (const float*)d_in[12];
    const float* Wc4a = (const float*)d_in[13];
    const float* Wc4b = (const float*)d_in[14];
    const float* Wc5a = (const float*)d_in[15];
    const float* Wc5b = (const float*)d_in[16];
    const float* Wc5r = (const float*)d_in[17];
    const float* Wc6a = (const float*)d_in[18];
    const float* Wc6b = (const float*)d_in[19];
    const float* Wc7a = (const float*)d_in[20];
    const float* Wc7b = (const float*)d_in[21];
    const float* Wc7r = (const float*)d_in[22];
    const float* Wc8a = (const float*)d_in[23];
    const float* Wc8b = (const float*)d_in[24];
    const float* Wlast = (const float*)d_in[25];
    const float* wlin  = (const float*)d_in[26];

    const size_t SZB = (size_t)BATCH * 103 * 103 * 8;
    const size_t SZM = (size_t)BATCH * 103 * 103;
    float* b0 = (float*)d_ws;
    float* b1 = b0 + SZB;
    float* b2 = b1 + SZB;
    float* m0 = b2 + SZB;
    float* m1 = m0 + SZM;

    const float* G[18];
    const float* Bt[18];
    for (int i = 0; i < 18; ++i) { G[i] = gamma + OFFS[i]; Bt[i] = beta + OFFS[i]; }

    auto pool = [&](const float* in, float* out, int Hin, int Hout, int win, int stride_) {
        int total = BATCH * Hout * Hout;
        pool_kernel<<<(total + 255) / 256, 256, 0, stream>>>(in, out, Hin, Hin, Hout, Hout, win, stride_);
    };

    // scatter into xs(b1), ms(b2)
    {
        int n = BATCH * S * S;
        zero2_kernel<<<(n / 4 + 255) / 256, 256, 0, stream>>>((float4*)b1, (float4*)b2, n / 4);
        scatter_kernel<<<(NPTS + 255) / 256, 256, 0, stream>>>(loc, bidx, feat, b1, b2);
        int total = BATCH * 103 * 103;
        conv0_pool_kernel<<<(total + 255) / 256, 256, 0, stream>>>(b1, b2, Wconv0, b0, m0);
    }
    // x = b0 (103,103,8), mask = m0

    // c1, c2: fused residual blocks at 103^2, C=8, 7x7 tiles of 16
    fused_pair_kernel<8, 16, 7><<<dim3(7 * 7 * BATCH), 256, 0, stream>>>(
        b0, m0, Wc1a, Wc1b, G[0], Bt[0], G[1], Bt[1], b1, 103);
    fused_pair_kernel<8, 16, 7><<<dim3(7 * 7 * BATCH), 256, 0, stream>>>(
        b1, m0, Wc2a, Wc2b, G[2], Bt[2], G[3], Bt[3], b2, 103);
    // x = b2
    // c3 (stride2, 103->51, 8->16)
    pool(m0, m1, 103, 51, 3, 2);
    fconv<3, 8, 16, 8, false, false>(stream, b2, Wc3r, nullptr, nullptr, nullptr, m1, nullptr, b0, 103, 51, 2, 0);
    fconv<3, 8, 16, 8, true,  false>(stream, b2, Wc3a, G[4], Bt[4], m0, m1, nullptr, b1, 103, 51, 2, 0);
    fconv<3, 16, 16, 8, true, true >(stream, b1, Wc3b, G[5], Bt[5], m1, m1, b0,      b2, 51, 51, 1, 1);
    // x = b2, mask = m1
    // c4
    fconv<3, 16, 16, 8, true, false>(stream, b2, Wc4a, G[6], Bt[6], m1, m1, nullptr, b0, 51, 51, 1, 1);
    fconv<3, 16, 16, 8, true, true >(stream, b0, Wc4b, G[7], Bt[7], m1, m1, b2,      b1, 51, 51, 1, 1);
    // x = b1
    // c5 (stride2, 51->25, 16->24)
    pool(m1, m0, 51, 25, 3, 2);
    fconv<3, 16, 24, 8, false, false>(stream, b1, Wc5r, nullptr, nullptr, nullptr, m0, nullptr, b0, 51, 25, 2, 0);
    fconv<3, 16, 24, 8, true,  false>(stream, b1, Wc5a, G[8], Bt[8], m1, m0, nullptr, b2, 51, 25, 2, 0);
    fconv<3, 24, 24, 8, true,  true >(stream, b2, Wc5b, G[9], Bt[9], m0, m0, b0,      b1, 25, 25, 1, 1);
    // x = b1, mask = m0
    // c6
    fconv<3, 24, 24, 8, true, false>(stream, b1, Wc6a, G[10], Bt[10], m0, m0, nullptr, b0, 25, 25, 1, 1);
    fconv<3, 24, 24, 8, true, true >(stream, b0, Wc6b, G[11], Bt[11], m0, m0, b1,      b2, 25, 25, 1, 1);
    // x = b2
    // c7 (stride2, 25->12, 24->32)
    pool(m0, m1, 25, 12, 3, 2);
    fconv<3, 24, 32, 8, false, false>(stream, b2, Wc7r, nullptr, nullptr, nullptr, m1, nullptr, b0, 25, 12, 2, 0);
    fconv<3, 24, 32, 8, true,  false>(stream, b2, Wc7a, G[12], Bt[12], m0, m1, nullptr, b1, 25, 12, 2, 0);
    fconv<3, 32, 32, 8, true,  true >(stream, b1, Wc7b, G[13], Bt[13], m1, m1, b0,      b2, 12, 12, 1, 1);
    // x = b2, mask = m1
    // c8
    fconv<3, 32, 32, 8, true, false>(stream, b2, Wc8a, G[14], Bt[14], m1, m1, nullptr, b0, 12, 12, 1, 1);
    fconv<3, 32, 32, 8, true, true >(stream, b0, Wc8b, G[15], Bt[15], m1, m1, b2,      b1, 12, 12, 1, 1);
    // x = b1
    // tail
    pool(m1, m0, 12, 8, 5, 1);
    fconv<5, 32, 64, 4, true, false>(stream, b1, Wlast, G[16], Bt[16], m1, m0, nullptr, b0, 12, 8, 1, 0);
    // linear: bnrelu+transpose, zero out, split-K GEMM with atomics
    bn_tr_kernel<<<(BATCH * 4096 + 255) / 256, 256, 0, stream>>>(b0, m0, G[17], Bt[17], b2);
    zero_kernel<<<(BATCH * 100 + 255) / 256, 256, 0, stream>>>((float*)d_out, BATCH * 100);
    linear_gemm_kernel<<<dim3(100, 8), 256, 0, stream>>>(b2, wlin, (float*)d_out);
}

// Round 4
// 1125.136 us; speedup vs baseline: 1.2993x; 1.2993x over previous
//
#include <hip/hip_runtime.h>

#define S 207
#define BATCH 128
#define NPTS 256000

static const int OFFS[19] = {0,8,16,24,32,40,56,72,88,104,128,152,176,200,232,264,296,328,392};

__global__ void zero2_kernel(float4* __restrict__ a, float4* __restrict__ b, int n4) {
    int i = blockIdx.x * blockDim.x + threadIdx.x;
    if (i < n4) { a[i] = make_float4(0,0,0,0); b[i] = make_float4(0,0,0,0); }
}

__global__ void zero_kernel(float* __restrict__ p, int n) {
    int i = blockIdx.x * blockDim.x + threadIdx.x;
    if (i < n) p[i] = 0.0f;
}

__global__ void scatter_kernel(const int* __restrict__ loc, const int* __restrict__ bidx,
                               const float* __restrict__ feat,
                               float* __restrict__ xs, float* __restrict__ ms) {
    int t = blockIdx.x * blockDim.x + threadIdx.x;
    if (t >= NPTS) return;
    int b = bidx[t];
    int r = loc[2 * t];
    int c = loc[2 * t + 1];
    int idx = (b * S + r) * S + c;
    atomicAdd(&xs[idx], feat[t]);
    ms[idx] = 1.0f;
}

// Fused conv0(SAME)*m -> masked 3x2 maxpool. One thread per output pixel, all 8 channels.
__global__ __launch_bounds__(256) void conv0_pool_kernel(
    const float* __restrict__ xs, const float* __restrict__ ms,
    const float* __restrict__ w,   // (3,3,1,8)
    float* __restrict__ x1, float* __restrict__ m1) {
    const int Hout = 103;
    int opix = blockIdx.x * 256 + threadIdx.x;
    int total = BATCH * Hout * Hout;
    if (opix >= total) return;
    int wo = opix % Hout;
    int t = opix / Hout;
    int ho = t % Hout;
    int b  = t / Hout;

    float mv[3][3];
    float mwin = 0.0f;
    #pragma unroll
    for (int pi = 0; pi < 3; ++pi)
        #pragma unroll
        for (int pj = 0; pj < 3; ++pj) {
            float m = ms[(b * S + 2 * ho + pi) * S + 2 * wo + pj];
            mv[pi][pj] = m;
            mwin = fmaxf(mwin, m);
        }
    float* xp = x1 + (size_t)opix * 8;
    if (mwin <= 0.0f) {
        *(float4*)xp = make_float4(0,0,0,0);
        *(float4*)(xp + 4) = make_float4(0,0,0,0);
        m1[opix] = 0.0f;
        return;
    }
    float p[5][5];
    #pragma unroll
    for (int r = 0; r < 5; ++r) {
        int ii = 2 * ho - 1 + r;
        #pragma unroll
        for (int c = 0; c < 5; ++c) {
            int jj = 2 * wo - 1 + c;
            bool ok = ((unsigned)ii < (unsigned)S) && ((unsigned)jj < (unsigned)S);
            p[r][c] = ok ? xs[(b * S + ii) * S + jj] : 0.0f;
        }
    }
    float best[8];
    #pragma unroll
    for (int co = 0; co < 8; ++co) best[co] = -1e30f;
    #pragma unroll
    for (int pi = 0; pi < 3; ++pi)
        #pragma unroll
        for (int pj = 0; pj < 3; ++pj) {
            if (mv[pi][pj] > 0.0f) {
                float acc[8];
                #pragma unroll
                for (int co = 0; co < 8; ++co) acc[co] = 0.0f;
                #pragma unroll
                for (int kh = 0; kh < 3; ++kh)
                    #pragma unroll
                    for (int kw = 0; kw < 3; ++kw) {
                        float x = p[pi + kh][pj + kw];
                        #pragma unroll
                        for (int co = 0; co < 8; ++co)
                            acc[co] = fmaf(x, w[(kh * 3 + kw) * 8 + co], acc[co]);
                    }
                #pragma unroll
                for (int co = 0; co < 8; ++co) best[co] = fmaxf(best[co], acc[co]);
            }
        }
    *(float4*)xp = make_float4(best[0], best[1], best[2], best[3]);
    *(float4*)(xp + 4) = make_float4(best[4], best[5], best[6], best[7]);
    m1[opix] = 1.0f;
}

// Fused conv: optionally bnrelu on input, conv, * mOut, [+ res].
template <int K, int CIN, int COUT, int COT, bool BN, bool RES>
__global__ __launch_bounds__(256) void fconv_kernel(
    const float* __restrict__ in, const float* __restrict__ w,
    const float* __restrict__ g, const float* __restrict__ bbn,
    const float* __restrict__ mIn, const float* __restrict__ mOut,
    const float* __restrict__ res, float* __restrict__ out,
    int Hin, int Hout, int stride, int pad) {
    const int Win = Hin, Wout = Hout;
    int npix = BATCH * Hout * Wout;
    int opix = blockIdx.x * 256 + threadIdx.x;
    if (opix >= npix) return;
    int co0 = blockIdx.y * COT;
    int wo = opix % Wout;
    int t = opix / Wout;
    int ho = t % Hout;
    int b  = t / Hout;

    float mo = mOut[opix];
    float* op = out + (size_t)opix * COUT + co0;
    if (mo <= 0.0f) {
        #pragma unroll
        for (int j = 0; j < COT; j += 4) {
            float4 r4 = RES ? *(const float4*)(res + (size_t)opix * COUT + co0 + j)
                            : make_float4(0,0,0,0);
            *(float4*)(op + j) = r4;
        }
        return;
    }
    float acc[COT];
    #pragma unroll
    for (int j = 0; j < COT; ++j) acc[j] = 0.0f;

    #pragma unroll
    for (int kh = 0; kh < K; ++kh) {
        int ih = ho * stride + kh - pad;
        if ((unsigned)ih >= (unsigned)Hin) continue;
        #pragma unroll
        for (int kw = 0; kw < K; ++kw) {
            int iw = wo * stride + kw - pad;
            if ((unsigned)iw >= (unsigned)Win) continue;
            int ipix = (b * Hin + ih) * Win + iw;
            float mi = 1.0f;
            if (BN) { mi = mIn[ipix]; if (mi <= 0.0f) continue; }
            const float* ip = in + (size_t)ipix * CIN;
            const float* wp = w + (kh * K + kw) * CIN * COUT + co0;
            #pragma unroll
            for (int ci = 0; ci < CIN; ci += 4) {
                float4 xv = *(const float4*)(ip + ci);
                if (BN) {
                    xv.x = mi * fmaxf(fmaf(xv.x, g[ci],     bbn[ci]),     0.0f);
                    xv.y = mi * fmaxf(fmaf(xv.y, g[ci + 1], bbn[ci + 1]), 0.0f);
                    xv.z = mi * fmaxf(fmaf(xv.z, g[ci + 2], bbn[ci + 2]), 0.0f);
                    xv.w = mi * fmaxf(fmaf(xv.w, g[ci + 3], bbn[ci + 3]), 0.0f);
                }
                #pragma unroll
                for (int j = 0; j < COT; ++j) {
                    acc[j] = fmaf(xv.x, wp[(ci    ) * COUT + j], acc[j]);
                    acc[j] = fmaf(xv.y, wp[(ci + 1) * COUT + j], acc[j]);
                    acc[j] = fmaf(xv.z, wp[(ci + 2) * COUT + j], acc[j]);
                    acc[j] = fmaf(xv.w, wp[(ci + 3) * COUT + j], acc[j]);
                }
            }
        }
    }
    #pragma unroll
    for (int j = 0; j < COT; j += 4) {
        float4 o4;
        o4.x = acc[j] * mo; o4.y = acc[j+1] * mo; o4.z = acc[j+2] * mo; o4.w = acc[j+3] * mo;
        if (RES) {
            float4 r4 = *(const float4*)(res + (size_t)opix * COUT + co0 + j);
            o4.x += r4.x; o4.y += r4.y; o4.z += r4.z; o4.w += r4.w;
        }
        *(float4*)(op + j) = o4;
    }
}

// Fused downsample stage: one read of x produces
//   m2   = maxpool3x3s2(mIn)                         -> mOutBuf
//   outA = conv3x3s2(bnrelu(x,mIn,g,b)) * m2          (main path)
//   outR = conv3x3s2(x) * m2                          (residual path)
// Exact tap-skip: x == 0 wherever mIn == 0 (network invariant).
template <int CIN, int COUT>
__global__ __launch_bounds__(256) void strided_ra_kernel(
    const float* __restrict__ in,
    const float* __restrict__ wR, const float* __restrict__ wA,
    const float* __restrict__ g, const float* __restrict__ bbn,
    const float* __restrict__ mIn, float* __restrict__ mOutBuf,
    float* __restrict__ outR, float* __restrict__ outA,
    int Hin, int Hout) {
    int npix = BATCH * Hout * Hout;
    int opix = blockIdx.x * 256 + threadIdx.x;
    if (opix >= npix) return;
    int wo = opix % Hout;
    int t = opix / Hout;
    int ho = t % Hout;
    int b  = t / Hout;

    float accR[COUT], accA[COUT];
    #pragma unroll
    for (int j = 0; j < COUT; ++j) { accR[j] = 0.0f; accA[j] = 0.0f; }
    float m2 = 0.0f;

    #pragma unroll
    for (int kh = 0; kh < 3; ++kh) {
        int ih = 2 * ho + kh;
        #pragma unroll
        for (int kw = 0; kw < 3; ++kw) {
            int iw = 2 * wo + kw;
            int ipix = (b * Hin + ih) * Hin + iw;
            float mi = mIn[ipix];
            if (mi <= 0.0f) continue;
            m2 = fmaxf(m2, mi);
            const float* ip  = in + (size_t)ipix * CIN;
            const float* wpR = wR + (kh * 3 + kw) * CIN * COUT;
            const float* wpA = wA + (kh * 3 + kw) * CIN * COUT;
            #pragma unroll
            for (int ci = 0; ci < CIN; ci += 4) {
                float4 xv = *(const float4*)(ip + ci);
                float4 hv;
                hv.x = mi * fmaxf(fmaf(xv.x, g[ci],     bbn[ci]),     0.0f);
                hv.y = mi * fmaxf(fmaf(xv.y, g[ci + 1], bbn[ci + 1]), 0.0f);
                hv.z = mi * fmaxf(fmaf(xv.z, g[ci + 2], bbn[ci + 2]), 0.0f);
                hv.w = mi * fmaxf(fmaf(xv.w, g[ci + 3], bbn[ci + 3]), 0.0f);
                #pragma unroll
                for (int j = 0; j < COUT; ++j) {
                    accR[j] = fmaf(xv.x, wpR[(ci    ) * COUT + j], accR[j]);
                    accR[j] = fmaf(xv.y, wpR[(ci + 1) * COUT + j], accR[j]);
                    accR[j] = fmaf(xv.z, wpR[(ci + 2) * COUT + j], accR[j]);
                    accR[j] = fmaf(xv.w, wpR[(ci + 3) * COUT + j], accR[j]);
                    accA[j] = fmaf(hv.x, wpA[(ci    ) * COUT + j], accA[j]);
                    accA[j] = fmaf(hv.y, wpA[(ci + 1) * COUT + j], accA[j]);
                    accA[j] = fmaf(hv.z, wpA[(ci + 2) * COUT + j], accA[j]);
                    accA[j] = fmaf(hv.w, wpA[(ci + 3) * COUT + j], accA[j]);
                }
            }
        }
    }
    mOutBuf[opix] = m2;
    float* opR = outR + (size_t)opix * COUT;
    float* opA = outA + (size_t)opix * COUT;
    #pragma unroll
    for (int j = 0; j < COUT; j += 4) {
        float4 r4, a4;
        r4.x = accR[j] * m2; r4.y = accR[j+1] * m2; r4.z = accR[j+2] * m2; r4.w = accR[j+3] * m2;
        a4.x = accA[j] * m2; a4.y = accA[j+1] * m2; a4.z = accA[j+2] * m2; a4.w = accA[j+3] * m2;
        *(float4*)(opR + j) = r4;
        *(float4*)(opA + j) = a4;
    }
}

__global__ void pool_kernel(const float* __restrict__ in, float* __restrict__ out,
                            int Hin, int Win, int Hout, int Wout, int win, int stride) {
    int tid = blockIdx.x * blockDim.x + threadIdx.x;
    int total = BATCH * Hout * Wout;
    if (tid >= total) return;
    int wo = tid % Wout;
    int p = tid / Wout;
    int ho = p % Hout;
    int b  = p / Hout;
    float mx = 0.0f;
    for (int i = 0; i < win; ++i)
        for (int j = 0; j < win; ++j)
            mx = fmaxf(mx, in[(b * Hin + ho * stride + i) * Win + wo * stride + j]);
    out[tid] = mx;
}

// bnrelu(g17,b17) + flatten to NCHW-flat layout: xt[b][c*64+hw]
__global__ __launch_bounds__(256) void bn_tr_kernel(
    const float* __restrict__ x, const float* __restrict__ m,
    const float* __restrict__ g, const float* __restrict__ bb,
    float* __restrict__ xt) {
    int tid = blockIdx.x * 256 + threadIdx.x;
    if (tid >= BATCH * 4096) return;
    int c = tid & 63, hw = (tid >> 6) & 63, b = tid >> 12;
    float v = m[b * 64 + hw] * fmaxf(fmaf(x[tid], g[c], bb[c]), 0.0f);
    xt[((size_t)b << 12) + c * 64 + hw] = v;
}

// C[128,100] += xt[128,4096] . wl[100,4096]^T, split-K with atomics.
__global__ __launch_bounds__(256) void linear_gemm_kernel(
    const float* __restrict__ xt, const float* __restrict__ wl,
    float* __restrict__ out) {
    int o = blockIdx.x;
    int half = threadIdx.x >> 7;
    int b = threadIdx.x & 127;
    int k0 = blockIdx.y * 512 + half * 256;
    const float* xp = xt + ((size_t)b << 12) + k0;
    const float* wp = wl + o * 4096 + k0;
    float acc = 0.0f;
    #pragma unroll 16
    for (int k = 0; k < 256; k += 4) {
        float4 xv = *(const float4*)(xp + k);
        float4 wv = *(const float4*)(wp + k);
        acc = fmaf(xv.x, wv.x, acc); acc = fmaf(xv.y, wv.y, acc);
        acc = fmaf(xv.z, wv.z, acc); acc = fmaf(xv.w, wv.w, acc);
    }
    atomicAdd(&out[b * 100 + o], acc);
}

template <int K, int CIN, int COUT, int COT, bool BN, bool RES>
static inline void fconv(hipStream_t s, const float* in, const float* w,
                         const float* g, const float* bbn,
                         const float* mIn, const float* mOut, const float* res,
                         float* out, int Hin, int Hout, int stride, int pad) {
    int npix = BATCH * Hout * Hout;
    dim3 grid((npix + 255) / 256, COUT / COT);
    fconv_kernel<K, CIN, COUT, COT, BN, RES><<<grid, 256, 0, s>>>(
        in, w, g, bbn, mIn, mOut, res, out, Hin, Hout, stride, pad);
}

template <int CIN, int COUT>
static inline void strided_ra(hipStream_t s, const float* in, const float* wR, const float* wA,
                              const float* g, const float* bbn, const float* mIn,
                              float* mOutBuf, float* outR, float* outA, int Hin, int Hout) {
    int npix = BATCH * Hout * Hout;
    strided_ra_kernel<CIN, COUT><<<(npix + 255) / 256, 256, 0, s>>>(
        in, wR, wA, g, bbn, mIn, mOutBuf, outR, outA, Hin, Hout);
}

extern "C" void kernel_launch(void* const* d_in, const int* in_sizes, int n_in,
                              void* d_out, int out_size, void* d_ws, size_t ws_size,
                              hipStream_t stream) {
    const int*   loc   = (const int*)d_in[0];
    const int*   bidx  = (const int*)d_in[1];
    const float* feat  = (const float*)d_in[2];
    const float* gamma = (const float*)d_in[3];
    const float* beta  = (const float*)d_in[4];
    const float* Wconv0 = (const float*)d_in[5];
    const float* Wc1a = (const float*)d_in[6];
    const float* Wc1b = (const float*)d_in[7];
    const float* Wc2a = (const float*)d_in[8];
    const float* Wc2b = (const float*)d_in[9];
    const float* Wc3a = (const float*)d_in[10];
    const float* Wc3b = (const float*)d_in[11];
    const float* Wc3r = (const float*)d_in[12];
    const float* Wc4a = (const float*)d_in[13];
    const float* Wc4b = (const float*)d_in[14];
    const float* Wc5a = (const float*)d_in[15];
    const float* Wc5b = (const float*)d_in[16];
    const float* Wc5r = (const float*)d_in[17];
    const float* Wc6a = (const float*)d_in[18];
    const float* Wc6b = (const float*)d_in[19];
    const float* Wc7a = (const float*)d_in[20];
    const float* Wc7b = (const float*)d_in[21];
    const float* Wc7r = (const float*)d_in[22];
    const float* Wc8a = (const float*)d_in[23];
    const float* Wc8b = (const float*)d_in[24];
    const float* Wlast = (const float*)d_in[25];
    const float* wlin  = (const float*)d_in[26];

    const size_t SZB = (size_t)BATCH * 103 * 103 * 8;
    const size_t SZM = (size_t)BATCH * 103 * 103;
    float* b0 = (float*)d_ws;
    float* b1 = b0 + SZB;
    float* b2 = b1 + SZB;
    float* m0 = b2 + SZB;
    float* m1 = m0 + SZM;

    const float* G[18];
    const float* Bt[18];
    for (int i = 0; i < 18; ++i) { G[i] = gamma + OFFS[i]; Bt[i] = beta + OFFS[i]; }

    // scatter into xs(b1), ms(b2)
    {
        int n = BATCH * S * S;
        zero2_kernel<<<(n / 4 + 255) / 256, 256, 0, stream>>>((float4*)b1, (float4*)b2, n / 4);
        scatter_kernel<<<(NPTS + 255) / 256, 256, 0, stream>>>(loc, bidx, feat, b1, b2);
        int total = BATCH * 103 * 103;
        conv0_pool_kernel<<<(total + 255) / 256, 256, 0, stream>>>(b1, b2, Wconv0, b0, m0);
    }
    // x = b0 (103,103,8), mask = m0

    // c1 (stride1, 103, 8ch)
    fconv<3, 8, 8, 8, true, false>(stream, b0, Wc1a, G[0], Bt[0], m0, m0, nullptr, b1, 103, 103, 1, 1);
    fconv<3, 8, 8, 8, true, true >(stream, b1, Wc1b, G[1], Bt[1], m0, m0, b0,      b2, 103, 103, 1, 1);
    // c2
    fconv<3, 8, 8, 8, true, false>(stream, b2, Wc2a, G[2], Bt[2], m0, m0, nullptr, b0, 103, 103, 1, 1);
    fconv<3, 8, 8, 8, true, true >(stream, b0, Wc2b, G[3], Bt[3], m0, m0, b2,      b1, 103, 103, 1, 1);
    // x = b1, mask = m0
    // c3 (stride2, 103->51, 8->16): fused r+a+maskpool
    strided_ra<8, 16>(stream, b1, Wc3r, Wc3a, G[4], Bt[4], m0, m1, b0, b2, 103, 51);
    fconv<3, 16, 16, 8, true, true >(stream, b2, Wc3b, G[5], Bt[5], m1, m1, b0, b1, 51, 51, 1, 1);
    // x = b1, mask = m1
    // c4
    fconv<3, 16, 16, 8, true, false>(stream, b1, Wc4a, G[6], Bt[6], m1, m1, nullptr, b0, 51, 51, 1, 1);
    fconv<3, 16, 16, 8, true, true >(stream, b0, Wc4b, G[7], Bt[7], m1, m1, b1,      b2, 51, 51, 1, 1);
    // x = b2
    // c5 (stride2, 51->25, 16->24)
    strided_ra<16, 24>(stream, b2, Wc5r, Wc5a, G[8], Bt[8], m1, m0, b0, b1, 51, 25);
    fconv<3, 24, 24, 8, true, true >(stream, b1, Wc5b, G[9], Bt[9], m0, m0, b0, b2, 25, 25, 1, 1);
    // x = b2, mask = m0
    // c6
    fconv<3, 24, 24, 8, true, false>(stream, b2, Wc6a, G[10], Bt[10], m0, m0, nullptr, b0, 25, 25, 1, 1);
    fconv<3, 24, 24, 8, true, true >(stream, b0, Wc6b, G[11], Bt[11], m0, m0, b2,      b1, 25, 25, 1, 1);
    // x = b1
    // c7 (stride2, 25->12, 24->32)
    strided_ra<24, 32>(stream, b1, Wc7r, Wc7a, G[12], Bt[12], m0, m1, b0, b2, 25, 12);
    fconv<3, 32, 32, 8, true, true >(stream, b2, Wc7b, G[13], Bt[13], m1, m1, b0, b1, 12, 12, 1, 1);
    // x = b1, mask = m1
    // c8
    fconv<3, 32, 32, 8, true, false>(stream, b1, Wc8a, G[14], Bt[14], m1, m1, nullptr, b0, 12, 12, 1, 1);
    fconv<3, 32, 32, 8, true, true >(stream, b0, Wc8b, G[15], Bt[15], m1, m1, b1,      b2, 12, 12, 1, 1);
    // x = b2
    // tail
    pool_kernel<<<(BATCH * 64 + 255) / 256, 256, 0, stream>>>(m1, m0, 12, 12, 8, 8, 5, 1);
    fconv<5, 32, 64, 4, true, false>(stream, b2, Wlast, G[16], Bt[16], m1, m0, nullptr, b0, 12, 8, 1, 0);
    bn_tr_kernel<<<(BATCH * 4096 + 255) / 256, 256, 0, stream>>>(b0, m0, G[17], Bt[17], b1);
    zero_kernel<<<(BATCH * 100 + 255) / 256, 256, 0, stream>>>((float*)d_out, BATCH * 100);
    linear_gemm_kernel<<<dim3(100, 8), 256, 0, stream>>>(b1, wlin, (float*)d_out);
}

// Round 5
// 907.907 us; speedup vs baseline: 1.6102x; 1.2393x over previous
//
#include <hip/hip_runtime.h>

#define S 207
#define BATCH 128
#define NPTS 256000

static const int OFFS[19] = {0,8,16,24,32,40,56,72,88,104,128,152,176,200,232,264,296,328,392};

__global__ void zero2_kernel(float4* __restrict__ a, float4* __restrict__ b, int n4) {
    int i = blockIdx.x * blockDim.x + threadIdx.x;
    if (i < n4) { a[i] = make_float4(0,0,0,0); b[i] = make_float4(0,0,0,0); }
}

__global__ void zero_kernel(float* __restrict__ p, int n) {
    int i = blockIdx.x * blockDim.x + threadIdx.x;
    if (i < n) p[i] = 0.0f;
}

__global__ void scatter_kernel(const int* __restrict__ loc, const int* __restrict__ bidx,
                               const float* __restrict__ feat,
                               float* __restrict__ xs, float* __restrict__ ms) {
    int t = blockIdx.x * blockDim.x + threadIdx.x;
    if (t >= NPTS) return;
    int b = bidx[t];
    int r = loc[2 * t];
    int c = loc[2 * t + 1];
    int idx = (b * S + r) * S + c;
    atomicAdd(&xs[idx], feat[t]);
    ms[idx] = 1.0f;
}

// Fused conv0(SAME)*m -> masked 3x2 maxpool. One thread per output pixel, all 8 channels.
__global__ __launch_bounds__(256) void conv0_pool_kernel(
    const float* __restrict__ xs, const float* __restrict__ ms,
    const float* __restrict__ w,   // (3,3,1,8)
    float* __restrict__ x1, float* __restrict__ m1) {
    const int Hout = 103;
    int opix = blockIdx.x * 256 + threadIdx.x;
    int total = BATCH * Hout * Hout;
    if (opix >= total) return;
    int wo = opix % Hout;
    int t = opix / Hout;
    int ho = t % Hout;
    int b  = t / Hout;

    float mv[3][3];
    float mwin = 0.0f;
    #pragma unroll
    for (int pi = 0; pi < 3; ++pi)
        #pragma unroll
        for (int pj = 0; pj < 3; ++pj) {
            float m = ms[(b * S + 2 * ho + pi) * S + 2 * wo + pj];
            mv[pi][pj] = m;
            mwin = fmaxf(mwin, m);
        }
    float* xp = x1 + (size_t)opix * 8;
    if (mwin <= 0.0f) {
        *(float4*)xp = make_float4(0,0,0,0);
        *(float4*)(xp + 4) = make_float4(0,0,0,0);
        m1[opix] = 0.0f;
        return;
    }
    float p[5][5];
    #pragma unroll
    for (int r = 0; r < 5; ++r) {
        int ii = 2 * ho - 1 + r;
        #pragma unroll
        for (int c = 0; c < 5; ++c) {
            int jj = 2 * wo - 1 + c;
            bool ok = ((unsigned)ii < (unsigned)S) && ((unsigned)jj < (unsigned)S);
            p[r][c] = ok ? xs[(b * S + ii) * S + jj] : 0.0f;
        }
    }
    float best[8];
    #pragma unroll
    for (int co = 0; co < 8; ++co) best[co] = -1e30f;
    #pragma unroll
    for (int pi = 0; pi < 3; ++pi)
        #pragma unroll
        for (int pj = 0; pj < 3; ++pj) {
            if (mv[pi][pj] > 0.0f) {
                float acc[8];
                #pragma unroll
                for (int co = 0; co < 8; ++co) acc[co] = 0.0f;
                #pragma unroll
                for (int kh = 0; kh < 3; ++kh)
                    #pragma unroll
                    for (int kw = 0; kw < 3; ++kw) {
                        float x = p[pi + kh][pj + kw];
                        #pragma unroll
                        for (int co = 0; co < 8; ++co)
                            acc[co] = fmaf(x, w[(kh * 3 + kw) * 8 + co], acc[co]);
                    }
                #pragma unroll
                for (int co = 0; co < 8; ++co) best[co] = fmaxf(best[co], acc[co]);
            }
        }
    *(float4*)xp = make_float4(best[0], best[1], best[2], best[3]);
    *(float4*)(xp + 4) = make_float4(best[4], best[5], best[6], best[7]);
    m1[opix] = 1.0f;
}

// Fused conv: optionally bnrelu on input, conv, * mOut, [+ res].
template <int K, int CIN, int COUT, int COT, bool BN, bool RES>
__global__ __launch_bounds__(256) void fconv_kernel(
    const float* __restrict__ in, const float* __restrict__ w,
    const float* __restrict__ g, const float* __restrict__ bbn,
    const float* __restrict__ mIn, const float* __restrict__ mOut,
    const float* __restrict__ res, float* __restrict__ out,
    int Hin, int Hout, int stride, int pad) {
    const int Win = Hin, Wout = Hout;
    int npix = BATCH * Hout * Wout;
    int opix = blockIdx.x * 256 + threadIdx.x;
    if (opix >= npix) return;
    int co0 = blockIdx.y * COT;
    int wo = opix % Wout;
    int t = opix / Wout;
    int ho = t % Hout;
    int b  = t / Hout;

    float mo = mOut[opix];
    float* op = out + (size_t)opix * COUT + co0;
    if (mo <= 0.0f) {
        #pragma unroll
        for (int j = 0; j < COT; j += 4) {
            float4 r4 = RES ? *(const float4*)(res + (size_t)opix * COUT + co0 + j)
                            : make_float4(0,0,0,0);
            *(float4*)(op + j) = r4;
        }
        return;
    }
    float acc[COT];
    #pragma unroll
    for (int j = 0; j < COT; ++j) acc[j] = 0.0f;

    #pragma unroll
    for (int kh = 0; kh < K; ++kh) {
        int ih = ho * stride + kh - pad;
        if ((unsigned)ih >= (unsigned)Hin) continue;
        #pragma unroll
        for (int kw = 0; kw < K; ++kw) {
            int iw = wo * stride + kw - pad;
            if ((unsigned)iw >= (unsigned)Win) continue;
            int ipix = (b * Hin + ih) * Win + iw;
            float mi = 1.0f;
            if (BN) { mi = mIn[ipix]; if (mi <= 0.0f) continue; }
            const float* ip = in + (size_t)ipix * CIN;
            const float* wp = w + (kh * K + kw) * CIN * COUT + co0;
            #pragma unroll
            for (int ci = 0; ci < CIN; ci += 4) {
                float4 xv = *(const float4*)(ip + ci);
                if (BN) {
                    xv.x = mi * fmaxf(fmaf(xv.x, g[ci],     bbn[ci]),     0.0f);
                    xv.y = mi * fmaxf(fmaf(xv.y, g[ci + 1], bbn[ci + 1]), 0.0f);
                    xv.z = mi * fmaxf(fmaf(xv.z, g[ci + 2], bbn[ci + 2]), 0.0f);
                    xv.w = mi * fmaxf(fmaf(xv.w, g[ci + 3], bbn[ci + 3]), 0.0f);
                }
                #pragma unroll
                for (int j = 0; j < COT; ++j) {
                    acc[j] = fmaf(xv.x, wp[(ci    ) * COUT + j], acc[j]);
                    acc[j] = fmaf(xv.y, wp[(ci + 1) * COUT + j], acc[j]);
                    acc[j] = fmaf(xv.z, wp[(ci + 2) * COUT + j], acc[j]);
                    acc[j] = fmaf(xv.w, wp[(ci + 3) * COUT + j], acc[j]);
                }
            }
        }
    }
    #pragma unroll
    for (int j = 0; j < COT; j += 4) {
        float4 o4;
        o4.x = acc[j] * mo; o4.y = acc[j+1] * mo; o4.z = acc[j+2] * mo; o4.w = acc[j+3] * mo;
        if (RES) {
            float4 r4 = *(const float4*)(res + (size_t)opix * COUT + co0 + j);
            o4.x += r4.x; o4.y += r4.y; o4.z += r4.z; o4.w += r4.w;
        }
        *(float4*)(op + j) = o4;
    }
}

// Fused downsample stage, parallel over (pixel-blocks, path x channel-group):
//   m2   = maxpool3x3s2(mIn)            (written by blockIdx.y == 0)
//   path 0: outR = conv3x3s2(x) * m2
//   path 1: outA = conv3x3s2(bnrelu(x,mIn,g,b)) * m2
template <int CIN, int COUT, int COT>
__global__ __launch_bounds__(256) void strided_ra_kernel(
    const float* __restrict__ in,
    const float* __restrict__ wR, const float* __restrict__ wA,
    const float* __restrict__ g, const float* __restrict__ bbn,
    const float* __restrict__ mIn, float* __restrict__ mOutBuf,
    float* __restrict__ outR, float* __restrict__ outA,
    int Hin, int Hout) {
    constexpr int NG = COUT / COT;
    int npix = BATCH * Hout * Hout;
    int opix = blockIdx.x * 256 + threadIdx.x;
    if (opix >= npix) return;
    int path = blockIdx.y / NG;          // 0 = residual (raw), 1 = main (bnrelu)
    int co0  = (blockIdx.y % NG) * COT;
    int wo = opix % Hout;
    int t = opix / Hout;
    int ho = t % Hout;
    int b  = t / Hout;

    const float* wsel = path ? wA : wR;
    float acc[COT];
    #pragma unroll
    for (int j = 0; j < COT; ++j) acc[j] = 0.0f;
    float m2 = 0.0f;

    #pragma unroll
    for (int kh = 0; kh < 3; ++kh) {
        int ih = 2 * ho + kh;
        #pragma unroll
        for (int kw = 0; kw < 3; ++kw) {
            int iw = 2 * wo + kw;
            int ipix = (b * Hin + ih) * Hin + iw;
            float mi = mIn[ipix];
            if (mi <= 0.0f) continue;
            m2 = fmaxf(m2, mi);
            const float* ip = in + (size_t)ipix * CIN;
            const float* wp = wsel + (kh * 3 + kw) * CIN * COUT + co0;
            #pragma unroll
            for (int ci = 0; ci < CIN; ci += 4) {
                float4 xv = *(const float4*)(ip + ci);
                if (path) {
                    xv.x = mi * fmaxf(fmaf(xv.x, g[ci],     bbn[ci]),     0.0f);
                    xv.y = mi * fmaxf(fmaf(xv.y, g[ci + 1], bbn[ci + 1]), 0.0f);
                    xv.z = mi * fmaxf(fmaf(xv.z, g[ci + 2], bbn[ci + 2]), 0.0f);
                    xv.w = mi * fmaxf(fmaf(xv.w, g[ci + 3], bbn[ci + 3]), 0.0f);
                }
                #pragma unroll
                for (int j = 0; j < COT; ++j) {
                    acc[j] = fmaf(xv.x, wp[(ci    ) * COUT + j], acc[j]);
                    acc[j] = fmaf(xv.y, wp[(ci + 1) * COUT + j], acc[j]);
                    acc[j] = fmaf(xv.z, wp[(ci + 2) * COUT + j], acc[j]);
                    acc[j] = fmaf(xv.w, wp[(ci + 3) * COUT + j], acc[j]);
                }
            }
        }
    }
    if (blockIdx.y == 0) mOutBuf[opix] = m2;
    float* op = (path ? outA : outR) + (size_t)opix * COUT + co0;
    #pragma unroll
    for (int j = 0; j < COT; j += 4) {
        float4 o4;
        o4.x = acc[j] * m2; o4.y = acc[j+1] * m2; o4.z = acc[j+2] * m2; o4.w = acc[j+3] * m2;
        *(float4*)(op + j) = o4;
    }
}

__global__ void pool_kernel(const float* __restrict__ in, float* __restrict__ out,
                            int Hin, int Win, int Hout, int Wout, int win, int stride) {
    int tid = blockIdx.x * blockDim.x + threadIdx.x;
    int total = BATCH * Hout * Wout;
    if (tid >= total) return;
    int wo = tid % Wout;
    int p = tid / Wout;
    int ho = p % Hout;
    int b  = p / Hout;
    float mx = 0.0f;
    for (int i = 0; i < win; ++i)
        for (int j = 0; j < win; ++j)
            mx = fmaxf(mx, in[(b * Hin + ho * stride + i) * Win + wo * stride + j]);
    out[tid] = mx;
}

// bnrelu(g17,b17) + flatten to NCHW-flat layout: xt[b][c*64+hw]
__global__ __launch_bounds__(256) void bn_tr_kernel(
    const float* __restrict__ x, const float* __restrict__ m,
    const float* __restrict__ g, const float* __restrict__ bb,
    float* __restrict__ xt) {
    int tid = blockIdx.x * 256 + threadIdx.x;
    if (tid >= BATCH * 4096) return;
    int c = tid & 63, hw = (tid >> 6) & 63, b = tid >> 12;
    float v = m[b * 64 + hw] * fmaxf(fmaf(x[tid], g[c], bb[c]), 0.0f);
    xt[((size_t)b << 12) + c * 64 + hw] = v;
}

// C[128,100] += xt[128,4096] . wl[100,4096]^T, split-K with atomics.
__global__ __launch_bounds__(256) void linear_gemm_kernel(
    const float* __restrict__ xt, const float* __restrict__ wl,
    float* __restrict__ out) {
    int o = blockIdx.x;
    int half = threadIdx.x >> 7;
    int b = threadIdx.x & 127;
    int k0 = blockIdx.y * 512 + half * 256;
    const float* xp = xt + ((size_t)b << 12) + k0;
    const float* wp = wl + o * 4096 + k0;
    float acc = 0.0f;
    #pragma unroll 16
    for (int k = 0; k < 256; k += 4) {
        float4 xv = *(const float4*)(xp + k);
        float4 wv = *(const float4*)(wp + k);
        acc = fmaf(xv.x, wv.x, acc); acc = fmaf(xv.y, wv.y, acc);
        acc = fmaf(xv.z, wv.z, acc); acc = fmaf(xv.w, wv.w, acc);
    }
    atomicAdd(&out[b * 100 + o], acc);
}

template <int K, int CIN, int COUT, int COT, bool BN, bool RES>
static inline void fconv(hipStream_t s, const float* in, const float* w,
                         const float* g, const float* bbn,
                         const float* mIn, const float* mOut, const float* res,
                         float* out, int Hin, int Hout, int stride, int pad) {
    int npix = BATCH * Hout * Hout;
    dim3 grid((npix + 255) / 256, COUT / COT);
    fconv_kernel<K, CIN, COUT, COT, BN, RES><<<grid, 256, 0, s>>>(
        in, w, g, bbn, mIn, mOut, res, out, Hin, Hout, stride, pad);
}

template <int CIN, int COUT, int COT>
static inline void strided_ra(hipStream_t s, const float* in, const float* wR, const float* wA,
                              const float* g, const float* bbn, const float* mIn,
                              float* mOutBuf, float* outR, float* outA, int Hin, int Hout) {
    int npix = BATCH * Hout * Hout;
    dim3 grid((npix + 255) / 256, 2 * (COUT / COT));
    strided_ra_kernel<CIN, COUT, COT><<<grid, 256, 0, s>>>(
        in, wR, wA, g, bbn, mIn, mOutBuf, outR, outA, Hin, Hout);
}

extern "C" void kernel_launch(void* const* d_in, const int* in_sizes, int n_in,
                              void* d_out, int out_size, void* d_ws, size_t ws_size,
                              hipStream_t stream) {
    const int*   loc   = (const int*)d_in[0];
    const int*   bidx  = (const int*)d_in[1];
    const float* feat  = (const float*)d_in[2];
    const float* gamma = (const float*)d_in[3];
    const float* beta  = (const float*)d_in[4];
    const float* Wconv0 = (const float*)d_in[5];
    const float* Wc1a = (const float*)d_in[6];
    const float* Wc1b = (const float*)d_in[7];
    const float* Wc2a = (const float*)d_in[8];
    const float* Wc2b = (const float*)d_in[9];
    const float* Wc3a = (const float*)d_in[10];
    const float* Wc3b = (const float*)d_in[11];
    const float* Wc3r = (const float*)d_in[12];
    const float* Wc4a = (const float*)d_in[13];
    const float* Wc4b = (const float*)d_in[14];
    const float* Wc5a = (const float*)d_in[15];
    const float* Wc5b = (const float*)d_in[16];
    const float* Wc5r = (const float*)d_in[17];
    const float* Wc6a = (const float*)d_in[18];
    const float* Wc6b = (const float*)d_in[19];
    const float* Wc7a = (const float*)d_in[20];
    const float* Wc7b = (const float*)d_in[21];
    const float* Wc7r = (const float*)d_in[22];
    const float* Wc8a = (const float*)d_in[23];
    const float* Wc8b = (const float*)d_in[24];
    const float* Wlast = (const float*)d_in[25];
    const float* wlin  = (const float*)d_in[26];

    const size_t SZB = (size_t)BATCH * 103 * 103 * 8;
    const size_t SZM = (size_t)BATCH * 103 * 103;
    float* b0 = (float*)d_ws;
    float* b1 = b0 + SZB;
    float* b2 = b1 + SZB;
    float* m0 = b2 + SZB;
    float* m1 = m0 + SZM;

    const float* G[18];
    const float* Bt[18];
    for (int i = 0; i < 18; ++i) { G[i] = gamma + OFFS[i]; Bt[i] = beta + OFFS[i]; }

    // scatter into xs(b1), ms(b2)
    {
        int n = BATCH * S * S;
        zero2_kernel<<<(n / 4 + 255) / 256, 256, 0, stream>>>((float4*)b1, (float4*)b2, n / 4);
        scatter_kernel<<<(NPTS + 255) / 256, 256, 0, stream>>>(loc, bidx, feat, b1, b2);
        int total = BATCH * 103 * 103;
        conv0_pool_kernel<<<(total + 255) / 256, 256, 0, stream>>>(b1, b2, Wconv0, b0, m0);
    }
    // x = b0 (103,103,8), mask = m0

    // c1 (stride1, 103, 8ch)
    fconv<3, 8, 8, 8, true, false>(stream, b0, Wc1a, G[0], Bt[0], m0, m0, nullptr, b1, 103, 103, 1, 1);
    fconv<3, 8, 8, 8, true, true >(stream, b1, Wc1b, G[1], Bt[1], m0, m0, b0,      b2, 103, 103, 1, 1);
    // c2
    fconv<3, 8, 8, 8, true, false>(stream, b2, Wc2a, G[2], Bt[2], m0, m0, nullptr, b0, 103, 103, 1, 1);
    fconv<3, 8, 8, 8, true, true >(stream, b0, Wc2b, G[3], Bt[3], m0, m0, b2,      b1, 103, 103, 1, 1);
    // x = b1, mask = m0
    // c3 (stride2, 103->51, 8->16): fused r+a+maskpool, path x cgroup parallel
    strided_ra<8, 16, 8>(stream, b1, Wc3r, Wc3a, G[4], Bt[4], m0, m1, b0, b2, 103, 51);
    fconv<3, 16, 16, 8, true, true >(stream, b2, Wc3b, G[5], Bt[5], m1, m1, b0, b1, 51, 51, 1, 1);
    // x = b1, mask = m1
    // c4
    fconv<3, 16, 16, 8, true, false>(stream, b1, Wc4a, G[6], Bt[6], m1, m1, nullptr, b0, 51, 51, 1, 1);
    fconv<3, 16, 16, 8, true, true >(stream, b0, Wc4b, G[7], Bt[7], m1, m1, b1,      b2, 51, 51, 1, 1);
    // x = b2
    // c5 (stride2, 51->25, 16->24)
    strided_ra<16, 24, 8>(stream, b2, Wc5r, Wc5a, G[8], Bt[8], m1, m0, b0, b1, 51, 25);
    fconv<3, 24, 24, 8, true, true >(stream, b1, Wc5b, G[9], Bt[9], m0, m0, b0, b2, 25, 25, 1, 1);
    // x = b2, mask = m0
    // c6
    fconv<3, 24, 24, 8, true, false>(stream, b2, Wc6a, G[10], Bt[10], m0, m0, nullptr, b0, 25, 25, 1, 1);
    fconv<3, 24, 24, 8, true, true >(stream, b0, Wc6b, G[11], Bt[11], m0, m0, b2,      b1, 25, 25, 1, 1);
    // x = b1
    // c7 (stride2, 25->12, 24->32): COT=4 -> 1152 blocks
    strided_ra<24, 32, 4>(stream, b1, Wc7r, Wc7a, G[12], Bt[12], m0, m1, b0, b2, 25, 12);
    fconv<3, 32, 32, 4, true, true >(stream, b2, Wc7b, G[13], Bt[13], m1, m1, b0, b1, 12, 12, 1, 1);
    // x = b1, mask = m1
    // c8 (12^2: COT=4 for parallelism)
    fconv<3, 32, 32, 4, true, false>(stream, b1, Wc8a, G[14], Bt[14], m1, m1, nullptr, b0, 12, 12, 1, 1);
    fconv<3, 32, 32, 4, true, true >(stream, b0, Wc8b, G[15], Bt[15], m1, m1, b1,      b2, 12, 12, 1, 1);
    // x = b2
    // tail
    pool_kernel<<<(BATCH * 64 + 255) / 256, 256, 0, stream>>>(m1, m0, 12, 12, 8, 8, 5, 1);
    fconv<5, 32, 64, 4, true, false>(stream, b2, Wlast, G[16], Bt[16], m1, m0, nullptr, b0, 12, 8, 1, 0);
    bn_tr_kernel<<<(BATCH * 4096 + 255) / 256, 256, 0, stream>>>(b0, m0, G[17], Bt[17], b1);
    zero_kernel<<<(BATCH * 100 + 255) / 256, 256, 0, stream>>>((float*)d_out, BATCH * 100);
    linear_gemm_kernel<<<dim3(100, 8), 256, 0, stream>>>(b1, wlin, (float*)d_out);
}

// Round 6
// 801.981 us; speedup vs baseline: 1.8228x; 1.1321x over previous
//
#include <hip/hip_runtime.h>

#define S 207
#define BATCH 128
#define NPTS 256000

static const int OFFS[19] = {0,8,16,24,32,40,56,72,88,104,128,152,176,200,232,264,296,328,392};

__global__ void zero2_kernel(float4* __restrict__ a, float4* __restrict__ b, int n4) {
    int i = blockIdx.x * blockDim.x + threadIdx.x;
    if (i < n4) { a[i] = make_float4(0,0,0,0); b[i] = make_float4(0,0,0,0); }
}

__global__ void zero_kernel(float* __restrict__ p, int n) {
    int i = blockIdx.x * blockDim.x + threadIdx.x;
    if (i < n) p[i] = 0.0f;
}

__global__ void scatter_kernel(const int* __restrict__ loc, const int* __restrict__ bidx,
                               const float* __restrict__ feat,
                               float* __restrict__ xs, float* __restrict__ ms) {
    int t = blockIdx.x * blockDim.x + threadIdx.x;
    if (t >= NPTS) return;
    int b = bidx[t];
    int r = loc[2 * t];
    int c = loc[2 * t + 1];
    int idx = (b * S + r) * S + c;
    atomicAdd(&xs[idx], feat[t]);
    ms[idx] = 1.0f;
}

// Fused conv0(SAME)*m -> masked 3x2 maxpool. One thread per output pixel, all 8 channels.
__global__ __launch_bounds__(256) void conv0_pool_kernel(
    const float* __restrict__ xs, const float* __restrict__ ms,
    const float* __restrict__ w,   // (3,3,1,8)
    float* __restrict__ x1, float* __restrict__ m1) {
    const int Hout = 103;
    int opix = blockIdx.x * 256 + threadIdx.x;
    int total = BATCH * Hout * Hout;
    if (opix >= total) return;
    int wo = opix % Hout;
    int t = opix / Hout;
    int ho = t % Hout;
    int b  = t / Hout;

    float mv[3][3];
    float mwin = 0.0f;
    #pragma unroll
    for (int pi = 0; pi < 3; ++pi)
        #pragma unroll
        for (int pj = 0; pj < 3; ++pj) {
            float m = ms[(b * S + 2 * ho + pi) * S + 2 * wo + pj];
            mv[pi][pj] = m;
            mwin = fmaxf(mwin, m);
        }
    float* xp = x1 + (size_t)opix * 8;
    if (mwin <= 0.0f) {
        *(float4*)xp = make_float4(0,0,0,0);
        *(float4*)(xp + 4) = make_float4(0,0,0,0);
        m1[opix] = 0.0f;
        return;
    }
    float p[5][5];
    #pragma unroll
    for (int r = 0; r < 5; ++r) {
        int ii = 2 * ho - 1 + r;
        #pragma unroll
        for (int c = 0; c < 5; ++c) {
            int jj = 2 * wo - 1 + c;
            bool ok = ((unsigned)ii < (unsigned)S) && ((unsigned)jj < (unsigned)S);
            p[r][c] = ok ? xs[(b * S + ii) * S + jj] : 0.0f;
        }
    }
    float best[8];
    #pragma unroll
    for (int co = 0; co < 8; ++co) best[co] = -1e30f;
    #pragma unroll
    for (int pi = 0; pi < 3; ++pi)
        #pragma unroll
        for (int pj = 0; pj < 3; ++pj) {
            if (mv[pi][pj] > 0.0f) {
                float acc[8];
                #pragma unroll
                for (int co = 0; co < 8; ++co) acc[co] = 0.0f;
                #pragma unroll
                for (int kh = 0; kh < 3; ++kh)
                    #pragma unroll
                    for (int kw = 0; kw < 3; ++kw) {
                        float x = p[pi + kh][pj + kw];
                        #pragma unroll
                        for (int co = 0; co < 8; ++co)
                            acc[co] = fmaf(x, w[(kh * 3 + kw) * 8 + co], acc[co]);
                    }
                #pragma unroll
                for (int co = 0; co < 8; ++co) best[co] = fmaxf(best[co], acc[co]);
            }
        }
    *(float4*)xp = make_float4(best[0], best[1], best[2], best[3]);
    *(float4*)(xp + 4) = make_float4(best[4], best[5], best[6], best[7]);
    m1[opix] = 1.0f;
}

// Fused full residual block (stride 1, CIN==COUT==C), planar-LDS version.
// out = conv(bnrelu(conv(bnrelu(x))*m))*m + x. Weights read uniformly from
// global (scalar-cached); LDS holds per-channel PLANES so lane->pixel reads
// are stride-1 (conflict-free). Requires TILE*TILE == blockDim == 256.
template <int C, int TILE, int NTX>
__global__ __launch_bounds__(256) void resblock_kernel(
    const float* __restrict__ in, const float* __restrict__ mask,
    const float* __restrict__ w1, const float* __restrict__ w2,
    const float* __restrict__ g1, const float* __restrict__ bb1,
    const float* __restrict__ g2, const float* __restrict__ bb2,
    float* __restrict__ out, int H) {
    constexpr int XT = TILE + 4, HT = TILE + 2;
    constexpr int XA = XT * XT, HA = HT * HT;
    __shared__ float xs[C][XA];     // bnrelu1'd input, 2-halo
    __shared__ float h1[C][HA];     // bnrelu2'd intermediate, 1-halo
    __shared__ float msh[XA];

    int tid = threadIdx.x;
    int bid = blockIdx.x;
    int b = bid / (NTX * NTX);
    int t = bid % (NTX * NTX);
    int r0 = (t / NTX) * TILE, c0 = (t % NTX) * TILE;

    float gr[C], br[C];
    #pragma unroll
    for (int c = 0; c < C; ++c) { gr[c] = g1[c]; br[c] = bb1[c]; }

    // phase 1: load + bnrelu1 -> planar LDS (masked-out pixels skip the load)
    for (int i = tid; i < XA; i += 256) {
        int py = i / XT, px = i % XT;
        int gy = r0 - 2 + py, gx = c0 - 2 + px;
        bool ok = (unsigned)gy < (unsigned)H && (unsigned)gx < (unsigned)H;
        float m = 0.0f;
        if (ok) m = mask[(size_t)(b * H + gy) * H + gx];
        msh[i] = m;
        if (m > 0.0f) {
            const float* ip = in + ((size_t)(b * H + gy) * H + gx) * C;
            #pragma unroll
            for (int c = 0; c < C; ++c)
                xs[c][i] = m * fmaxf(fmaf(ip[c], gr[c], br[c]), 0.0f);
        } else {
            #pragma unroll
            for (int c = 0; c < C; ++c) xs[c][i] = 0.0f;
        }
    }
    #pragma unroll
    for (int c = 0; c < C; ++c) { gr[c] = g2[c]; br[c] = bb2[c]; }
    __syncthreads();

    // phase 2: conv1 over the 1-halo region; bnrelu2 fused into the store
    for (int pos = tid; pos < HA; pos += 256) {
        int py = pos / HT, px = pos % HT;
        float mc = msh[(py + 1) * XT + px + 1];
        float acc[C];
        #pragma unroll
        for (int co = 0; co < C; ++co) acc[co] = 0.0f;
        if (mc > 0.0f) {
            #pragma unroll
            for (int kh = 0; kh < 3; ++kh)
                #pragma unroll
                for (int kw = 0; kw < 3; ++kw) {
                    int pix = (py + kh) * XT + px + kw;
                    const float* wp = w1 + (kh * 3 + kw) * C * C;   // wave-uniform -> s_load
                    #pragma unroll
                    for (int ci = 0; ci < C; ++ci) {
                        float xv = xs[ci][pix];
                        #pragma unroll
                        for (int co = 0; co < C; ++co)
                            acc[co] = fmaf(xv, wp[ci * C + co], acc[co]);
                    }
                }
        }
        #pragma unroll
        for (int co = 0; co < C; ++co)
            h1[co][pos] = mc * fmaxf(fmaf(acc[co] * mc, gr[co], br[co]), 0.0f);
    }
    __syncthreads();

    // phase 3: conv2 at the TILE x TILE center + residual (re-read x, L2-hot)
    {
        int ty = tid / TILE, tx = tid % TILE;
        int gy = r0 + ty, gx = c0 + tx;
        if (gy < H && gx < H) {
            float mo = msh[(ty + 2) * XT + tx + 2];
            float acc[C];
            #pragma unroll
            for (int co = 0; co < C; ++co) acc[co] = 0.0f;
            if (mo > 0.0f) {
                #pragma unroll
                for (int kh = 0; kh < 3; ++kh)
                    #pragma unroll
                    for (int kw = 0; kw < 3; ++kw) {
                        int pix = (ty + kh) * HT + tx + kw;
                        const float* wp = w2 + (kh * 3 + kw) * C * C;
                        #pragma unroll
                        for (int ci = 0; ci < C; ++ci) {
                            float xv = h1[ci][pix];
                            #pragma unroll
                            for (int co = 0; co < C; ++co)
                                acc[co] = fmaf(xv, wp[ci * C + co], acc[co]);
                        }
                    }
            }
            const float* rp = in + ((size_t)(b * H + gy) * H + gx) * C;
            float* op = out + ((size_t)(b * H + gy) * H + gx) * C;
            #pragma unroll
            for (int j = 0; j < C; j += 4) {
                float4 r4 = *(const float4*)(rp + j);
                float4 o4;
                o4.x = fmaf(acc[j],     mo, r4.x);
                o4.y = fmaf(acc[j + 1], mo, r4.y);
                o4.z = fmaf(acc[j + 2], mo, r4.z);
                o4.w = fmaf(acc[j + 3], mo, r4.w);
                *(float4*)(op + j) = o4;
            }
        }
    }
}

// Fused conv: optionally bnrelu on input, conv, * mOut, [+ res].
template <int K, int CIN, int COUT, int COT, bool BN, bool RES>
__global__ __launch_bounds__(256) void fconv_kernel(
    const float* __restrict__ in, const float* __restrict__ w,
    const float* __restrict__ g, const float* __restrict__ bbn,
    const float* __restrict__ mIn, const float* __restrict__ mOut,
    const float* __restrict__ res, float* __restrict__ out,
    int Hin, int Hout, int stride, int pad) {
    const int Win = Hin, Wout = Hout;
    int npix = BATCH * Hout * Wout;
    int opix = blockIdx.x * 256 + threadIdx.x;
    if (opix >= npix) return;
    int co0 = blockIdx.y * COT;
    int wo = opix % Wout;
    int t = opix / Wout;
    int ho = t % Hout;
    int b  = t / Hout;

    float mo = mOut[opix];
    float* op = out + (size_t)opix * COUT + co0;
    if (mo <= 0.0f) {
        #pragma unroll
        for (int j = 0; j < COT; j += 4) {
            float4 r4 = RES ? *(const float4*)(res + (size_t)opix * COUT + co0 + j)
                            : make_float4(0,0,0,0);
            *(float4*)(op + j) = r4;
        }
        return;
    }
    float acc[COT];
    #pragma unroll
    for (int j = 0; j < COT; ++j) acc[j] = 0.0f;

    #pragma unroll
    for (int kh = 0; kh < K; ++kh) {
        int ih = ho * stride + kh - pad;
        if ((unsigned)ih >= (unsigned)Hin) continue;
        #pragma unroll
        for (int kw = 0; kw < K; ++kw) {
            int iw = wo * stride + kw - pad;
            if ((unsigned)iw >= (unsigned)Win) continue;
            int ipix = (b * Hin + ih) * Win + iw;
            float mi = 1.0f;
            if (BN) { mi = mIn[ipix]; if (mi <= 0.0f) continue; }
            const float* ip = in + (size_t)ipix * CIN;
            const float* wp = w + (kh * K + kw) * CIN * COUT + co0;
            #pragma unroll
            for (int ci = 0; ci < CIN; ci += 4) {
                float4 xv = *(const float4*)(ip + ci);
                if (BN) {
                    xv.x = mi * fmaxf(fmaf(xv.x, g[ci],     bbn[ci]),     0.0f);
                    xv.y = mi * fmaxf(fmaf(xv.y, g[ci + 1], bbn[ci + 1]), 0.0f);
                    xv.z = mi * fmaxf(fmaf(xv.z, g[ci + 2], bbn[ci + 2]), 0.0f);
                    xv.w = mi * fmaxf(fmaf(xv.w, g[ci + 3], bbn[ci + 3]), 0.0f);
                }
                #pragma unroll
                for (int j = 0; j < COT; ++j) {
                    acc[j] = fmaf(xv.x, wp[(ci    ) * COUT + j], acc[j]);
                    acc[j] = fmaf(xv.y, wp[(ci + 1) * COUT + j], acc[j]);
                    acc[j] = fmaf(xv.z, wp[(ci + 2) * COUT + j], acc[j]);
                    acc[j] = fmaf(xv.w, wp[(ci + 3) * COUT + j], acc[j]);
                }
            }
        }
    }
    #pragma unroll
    for (int j = 0; j < COT; j += 4) {
        float4 o4;
        o4.x = acc[j] * mo; o4.y = acc[j+1] * mo; o4.z = acc[j+2] * mo; o4.w = acc[j+3] * mo;
        if (RES) {
            float4 r4 = *(const float4*)(res + (size_t)opix * COUT + co0 + j);
            o4.x += r4.x; o4.y += r4.y; o4.z += r4.z; o4.w += r4.w;
        }
        *(float4*)(op + j) = o4;
    }
}

// Fused downsample stage, parallel over (pixel-blocks, path x channel-group):
//   m2 = maxpool3x3s2(mIn)  (written by blockIdx.y == 0)
//   path 0: outR = conv3x3s2(x) * m2 ; path 1: outA = conv3x3s2(bnrelu(x)) * m2
template <int CIN, int COUT, int COT>
__global__ __launch_bounds__(256) void strided_ra_kernel(
    const float* __restrict__ in,
    const float* __restrict__ wR, const float* __restrict__ wA,
    const float* __restrict__ g, const float* __restrict__ bbn,
    const float* __restrict__ mIn, float* __restrict__ mOutBuf,
    float* __restrict__ outR, float* __restrict__ outA,
    int Hin, int Hout) {
    constexpr int NG = COUT / COT;
    int npix = BATCH * Hout * Hout;
    int opix = blockIdx.x * 256 + threadIdx.x;
    if (opix >= npix) return;
    int path = blockIdx.y / NG;
    int co0  = (blockIdx.y % NG) * COT;
    int wo = opix % Hout;
    int t = opix / Hout;
    int ho = t % Hout;
    int b  = t / Hout;

    const float* wsel = path ? wA : wR;
    float acc[COT];
    #pragma unroll
    for (int j = 0; j < COT; ++j) acc[j] = 0.0f;
    float m2 = 0.0f;

    #pragma unroll
    for (int kh = 0; kh < 3; ++kh) {
        int ih = 2 * ho + kh;
        #pragma unroll
        for (int kw = 0; kw < 3; ++kw) {
            int iw = 2 * wo + kw;
            int ipix = (b * Hin + ih) * Hin + iw;
            float mi = mIn[ipix];
            if (mi <= 0.0f) continue;
            m2 = fmaxf(m2, mi);
            const float* ip = in + (size_t)ipix * CIN;
            const float* wp = wsel + (kh * 3 + kw) * CIN * COUT + co0;
            #pragma unroll
            for (int ci = 0; ci < CIN; ci += 4) {
                float4 xv = *(const float4*)(ip + ci);
                if (path) {
                    xv.x = mi * fmaxf(fmaf(xv.x, g[ci],     bbn[ci]),     0.0f);
                    xv.y = mi * fmaxf(fmaf(xv.y, g[ci + 1], bbn[ci + 1]), 0.0f);
                    xv.z = mi * fmaxf(fmaf(xv.z, g[ci + 2], bbn[ci + 2]), 0.0f);
                    xv.w = mi * fmaxf(fmaf(xv.w, g[ci + 3], bbn[ci + 3]), 0.0f);
                }
                #pragma unroll
                for (int j = 0; j < COT; ++j) {
                    acc[j] = fmaf(xv.x, wp[(ci    ) * COUT + j], acc[j]);
                    acc[j] = fmaf(xv.y, wp[(ci + 1) * COUT + j], acc[j]);
                    acc[j] = fmaf(xv.z, wp[(ci + 2) * COUT + j], acc[j]);
                    acc[j] = fmaf(xv.w, wp[(ci + 3) * COUT + j], acc[j]);
                }
            }
        }
    }
    if (blockIdx.y == 0) mOutBuf[opix] = m2;
    float* op = (path ? outA : outR) + (size_t)opix * COUT + co0;
    #pragma unroll
    for (int j = 0; j < COT; j += 4) {
        float4 o4;
        o4.x = acc[j] * m2; o4.y = acc[j+1] * m2; o4.z = acc[j+2] * m2; o4.w = acc[j+3] * m2;
        *(float4*)(op + j) = o4;
    }
}

__global__ void pool_kernel(const float* __restrict__ in, float* __restrict__ out,
                            int Hin, int Win, int Hout, int Wout, int win, int stride) {
    int tid = blockIdx.x * blockDim.x + threadIdx.x;
    int total = BATCH * Hout * Wout;
    if (tid >= total) return;
    int wo = tid % Wout;
    int p = tid / Wout;
    int ho = p % Hout;
    int b  = p / Hout;
    float mx = 0.0f;
    for (int i = 0; i < win; ++i)
        for (int j = 0; j < win; ++j)
            mx = fmaxf(mx, in[(b * Hin + ho * stride + i) * Win + wo * stride + j]);
    out[tid] = mx;
}

// bnrelu(g17,b17) + flatten to NCHW-flat layout: xt[b][c*64+hw]
__global__ __launch_bounds__(256) void bn_tr_kernel(
    const float* __restrict__ x, const float* __restrict__ m,
    const float* __restrict__ g, const float* __restrict__ bb,
    float* __restrict__ xt) {
    int tid = blockIdx.x * 256 + threadIdx.x;
    if (tid >= BATCH * 4096) return;
    int c = tid & 63, hw = (tid >> 6) & 63, b = tid >> 12;
    float v = m[b * 64 + hw] * fmaxf(fmaf(x[tid], g[c], bb[c]), 0.0f);
    xt[((size_t)b << 12) + c * 64 + hw] = v;
}

// C[128,100] += xt[128,4096] . wl[100,4096]^T, split-K with atomics.
__global__ __launch_bounds__(256) void linear_gemm_kernel(
    const float* __restrict__ xt, const float* __restrict__ wl,
    float* __restrict__ out) {
    int o = blockIdx.x;
    int half = threadIdx.x >> 7;
    int b = threadIdx.x & 127;
    int k0 = blockIdx.y * 512 + half * 256;
    const float* xp = xt + ((size_t)b << 12) + k0;
    const float* wp = wl + o * 4096 + k0;
    float acc = 0.0f;
    #pragma unroll 16
    for (int k = 0; k < 256; k += 4) {
        float4 xv = *(const float4*)(xp + k);
        float4 wv = *(const float4*)(wp + k);
        acc = fmaf(xv.x, wv.x, acc); acc = fmaf(xv.y, wv.y, acc);
        acc = fmaf(xv.z, wv.z, acc); acc = fmaf(xv.w, wv.w, acc);
    }
    atomicAdd(&out[b * 100 + o], acc);
}

template <int K, int CIN, int COUT, int COT, bool BN, bool RES>
static inline void fconv(hipStream_t s, const float* in, const float* w,
                         const float* g, const float* bbn,
                         const float* mIn, const float* mOut, const float* res,
                         float* out, int Hin, int Hout, int stride, int pad) {
    int npix = BATCH * Hout * Hout;
    dim3 grid((npix + 255) / 256, COUT / COT);
    fconv_kernel<K, CIN, COUT, COT, BN, RES><<<grid, 256, 0, s>>>(
        in, w, g, bbn, mIn, mOut, res, out, Hin, Hout, stride, pad);
}

template <int CIN, int COUT, int COT>
static inline void strided_ra(hipStream_t s, const float* in, const float* wR, const float* wA,
                              const float* g, const float* bbn, const float* mIn,
                              float* mOutBuf, float* outR, float* outA, int Hin, int Hout) {
    int npix = BATCH * Hout * Hout;
    dim3 grid((npix + 255) / 256, 2 * (COUT / COT));
    strided_ra_kernel<CIN, COUT, COT><<<grid, 256, 0, s>>>(
        in, wR, wA, g, bbn, mIn, mOutBuf, outR, outA, Hin, Hout);
}

extern "C" void kernel_launch(void* const* d_in, const int* in_sizes, int n_in,
                              void* d_out, int out_size, void* d_ws, size_t ws_size,
                              hipStream_t stream) {
    const int*   loc   = (const int*)d_in[0];
    const int*   bidx  = (const int*)d_in[1];
    const float* feat  = (const float*)d_in[2];
    const float* gamma = (const float*)d_in[3];
    const float* beta  = (const float*)d_in[4];
    const float* Wconv0 = (const float*)d_in[5];
    const float* Wc1a = (const float*)d_in[6];
    const float* Wc1b = (const float*)d_in[7];
    const float* Wc2a = (const float*)d_in[8];
    const float* Wc2b = (const float*)d_in[9];
    const float* Wc3a = (const float*)d_in[10];
    const float* Wc3b = (const float*)d_in[11];
    const float* Wc3r = (const float*)d_in[12];
    const float* Wc4a = (const float*)d_in[13];
    const float* Wc4b = (const float*)d_in[14];
    const float* Wc5a = (const float*)d_in[15];
    const float* Wc5b = (const float*)d_in[16];
    const float* Wc5r = (const float*)d_in[17];
    const float* Wc6a = (const float*)d_in[18];
    const float* Wc6b = (const float*)d_in[19];
    const float* Wc7a = (const float*)d_in[20];
    const float* Wc7b = (const float*)d_in[21];
    const float* Wc7r = (const float*)d_in[22];
    const float* Wc8a = (const float*)d_in[23];
    const float* Wc8b = (const float*)d_in[24];
    const float* Wlast = (const float*)d_in[25];
    const float* wlin  = (const float*)d_in[26];

    const size_t SZB = (size_t)BATCH * 103 * 103 * 8;
    const size_t SZM = (size_t)BATCH * 103 * 103;
    float* b0 = (float*)d_ws;
    float* b1 = b0 + SZB;
    float* b2 = b1 + SZB;
    float* m0 = b2 + SZB;
    float* m1 = m0 + SZM;

    const float* G[18];
    const float* Bt[18];
    for (int i = 0; i < 18; ++i) { G[i] = gamma + OFFS[i]; Bt[i] = beta + OFFS[i]; }

    // scatter into xs(b1), ms(b2)
    {
        int n = BATCH * S * S;
        zero2_kernel<<<(n / 4 + 255) / 256, 256, 0, stream>>>((float4*)b1, (float4*)b2, n / 4);
        scatter_kernel<<<(NPTS + 255) / 256, 256, 0, stream>>>(loc, bidx, feat, b1, b2);
        int total = BATCH * 103 * 103;
        conv0_pool_kernel<<<(total + 255) / 256, 256, 0, stream>>>(b1, b2, Wconv0, b0, m0);
    }
    // x = b0 (103,103,8), mask = m0

    // c1, c2: fused residual blocks (planar LDS, global-uniform weights)
    resblock_kernel<8, 16, 7><<<dim3(7 * 7 * BATCH), 256, 0, stream>>>(
        b0, m0, Wc1a, Wc1b, G[0], Bt[0], G[1], Bt[1], b1, 103);
    resblock_kernel<8, 16, 7><<<dim3(7 * 7 * BATCH), 256, 0, stream>>>(
        b1, m0, Wc2a, Wc2b, G[2], Bt[2], G[3], Bt[3], b2, 103);
    // x = b2
    // c3 (stride2, 103->51, 8->16): full-width COT=16, 2-way path split only
    strided_ra<8, 16, 16>(stream, b2, Wc3r, Wc3a, G[4], Bt[4], m0, m1, b0, b1, 103, 51);
    fconv<3, 16, 16, 8, true, true >(stream, b1, Wc3b, G[5], Bt[5], m1, m1, b0, b2, 51, 51, 1, 1);
    // x = b2, mask = m1
    // c4
    fconv<3, 16, 16, 8, true, false>(stream, b2, Wc4a, G[6], Bt[6], m1, m1, nullptr, b0, 51, 51, 1, 1);
    fconv<3, 16, 16, 8, true, true >(stream, b0, Wc4b, G[7], Bt[7], m1, m1, b2,      b1, 51, 51, 1, 1);
    // x = b1
    // c5 (stride2, 51->25, 16->24): full-width COT=24
    strided_ra<16, 24, 24>(stream, b1, Wc5r, Wc5a, G[8], Bt[8], m1, m0, b0, b2, 51, 25);
    fconv<3, 24, 24, 8, true, true >(stream, b2, Wc5b, G[9], Bt[9], m0, m0, b0, b1, 25, 25, 1, 1);
    // x = b1, mask = m0
    // c6
    fconv<3, 24, 24, 8, true, false>(stream, b1, Wc6a, G[10], Bt[10], m0, m0, nullptr, b0, 25, 25, 1, 1);
    fconv<3, 24, 24, 8, true, true >(stream, b0, Wc6b, G[11], Bt[11], m0, m0, b1,      b2, 25, 25, 1, 1);
    // x = b2
    // c7 (stride2, 25->12, 24->32): COT=8 (input is L2/L3-resident)
    strided_ra<24, 32, 8>(stream, b2, Wc7r, Wc7a, G[12], Bt[12], m0, m1, b0, b1, 25, 12);
    fconv<3, 32, 32, 4, true, true >(stream, b1, Wc7b, G[13], Bt[13], m1, m1, b0, b2, 12, 12, 1, 1);
    // x = b2, mask = m1
    // c8
    fconv<3, 32, 32, 4, true, false>(stream, b2, Wc8a, G[14], Bt[14], m1, m1, nullptr, b0, 12, 12, 1, 1);
    fconv<3, 32, 32, 4, true, true >(stream, b0, Wc8b, G[15], Bt[15], m1, m1, b2,      b1, 12, 12, 1, 1);
    // x = b1
    // tail
    pool_kernel<<<(BATCH * 64 + 255) / 256, 256, 0, stream>>>(m1, m0, 12, 12, 8, 8, 5, 1);
    fconv<5, 32, 64, 4, true, false>(stream, b1, Wlast, G[16], Bt[16], m1, m0, nullptr, b0, 12, 8, 1, 0);
    bn_tr_kernel<<<(BATCH * 4096 + 255) / 256, 256, 0, stream>>>(b0, m0, G[17], Bt[17], b2);
    zero_kernel<<<(BATCH * 100 + 255) / 256, 256, 0, stream>>>((float*)d_out, BATCH * 100);
    linear_gemm_kernel<<<dim3(100, 8), 256, 0, stream>>>(b2, wlin, (float*)d_out);
}